// Round 7
// baseline (715.257 us; speedup 1.0000x reference)
//
#include <hip/hip_runtime.h>

// GCN 3-layer, R7.
//  CSR build = two-level counting sort (bucket = 32 dst nodes):
//    bcount -> bscan -> bappend(tmp {src,dst}) -> countB (LDS per-node counts,
//    dense cnt write) -> scan1/2/3 (rowptr + dinv) -> fillB (LDS fill ctrs,
//    writes ew {src,w} into L2-resident per-bucket window).
//  fused_l2l3: wave per 8 nodes, lane=feature; per 64-edge chunk ONE coalesced
//    ew load + ONE per-lane a1[src] gather, then DYNAMIC-trip readlane loop
//    (exactly deg iterations, not 64 predicated).
//  logits = S z + c, 16-lane group per node.

#define NBSHIFT 5
#define NBNODES 32

__device__ __forceinline__ float rlane(float v, int l) {
    return __int_as_float(__builtin_amdgcn_readlane(__float_as_int(v), l));
}

// ---- bucket count ----
__global__ void bcount(const int* __restrict__ dst, int* __restrict__ bcnt, int E) {
    int e = blockIdx.x * blockDim.x + threadIdx.x;
    if (e < E) atomicAdd(&bcnt[dst[e] >> NBSHIFT], 1);
}

// single-block exclusive scan of bcnt[B] -> boff[B+1] (B <= 4095)
__global__ void bscan(const int* __restrict__ bcnt, int* __restrict__ boff, int B) {
    __shared__ int sums[1024];
    int t = threadIdx.x;
    int v[4]; int s = 0;
    #pragma unroll
    for (int k = 0; k < 4; ++k) { int i = t*4+k; v[k] = (i < B) ? bcnt[i] : 0; s += v[k]; }
    sums[t] = s; __syncthreads();
    for (int off = 1; off < 1024; off <<= 1) {
        int tv = (t >= off) ? sums[t-off] : 0;
        __syncthreads();
        sums[t] += tv;
        __syncthreads();
    }
    int excl = sums[t] - s;
    #pragma unroll
    for (int k = 0; k < 4; ++k) {
        int i = t*4+k;
        if (i <= B) boff[i] = excl;
        excl += v[k];
    }
}

// append {src,dst} into bucket segments (3125 open tails -> L2-resident)
__global__ void bappend(const int* __restrict__ src, const int* __restrict__ dst,
                        const int* __restrict__ boff, int* __restrict__ bfill,
                        uint2* __restrict__ tmp, int E) {
    int e = blockIdx.x * blockDim.x + threadIdx.x;
    if (e >= E) return;
    int d = dst[e];
    int b = d >> NBSHIFT;
    int p = boff[b] + atomicAdd(&bfill[b], 1);
    tmp[p] = make_uint2((unsigned)src[e], (unsigned)d);
}

// per-node degree via LDS counters, dense write (no global atomics, no memset)
__global__ void countB(const uint2* __restrict__ tmp, const int* __restrict__ boff,
                       int* __restrict__ cnt, int N) {
    __shared__ int lc[NBNODES];
    int b = blockIdx.x, t = threadIdx.x;
    if (t < NBNODES) lc[t] = 0;
    __syncthreads();
    int p0 = boff[b], p1 = boff[b+1];
    for (int p = p0 + t; p < p1; p += 256) atomicAdd(&lc[tmp[p].y & (NBNODES-1)], 1);
    __syncthreads();
    int node = b * NBNODES + t;
    if (t < NBNODES && node < N) cnt[node] = lc[t];
}

// exclusive scan phase 1 (+ dinv fused)
__global__ void scan1(const int* __restrict__ cnt, int* __restrict__ rowptr,
                      int* __restrict__ bsums, float* __restrict__ dinv, int N) {
    __shared__ int tmp[256];
    int i = blockIdx.x * 256 + threadIdx.x;
    int v = (i < N) ? cnt[i] : 0;
    if (i < N) dinv[i] = rsqrtf((float)(v + 1));
    tmp[threadIdx.x] = v; __syncthreads();
    for (int off = 1; off < 256; off <<= 1) {
        int t = (threadIdx.x >= off) ? tmp[threadIdx.x - off] : 0;
        __syncthreads();
        tmp[threadIdx.x] += t;
        __syncthreads();
    }
    if (i < N) rowptr[i] = tmp[threadIdx.x] - v;
    if (threadIdx.x == 255) bsums[blockIdx.x] = tmp[255];
}

__global__ void scan2(int* __restrict__ bsums, int nb) {    // 1 block, 1024 thr
    __shared__ int tmp[1024];
    int v = (threadIdx.x < nb) ? bsums[threadIdx.x] : 0;
    tmp[threadIdx.x] = v; __syncthreads();
    for (int off = 1; off < 1024; off <<= 1) {
        int t = (threadIdx.x >= off) ? tmp[threadIdx.x - off] : 0;
        __syncthreads();
        tmp[threadIdx.x] += t;
        __syncthreads();
    }
    if (threadIdx.x < nb) bsums[threadIdx.x] = tmp[threadIdx.x] - v;
}

__global__ void scan3(int* __restrict__ rowptr, const int* __restrict__ bsums, int N, int E) {
    int i = blockIdx.x * 256 + threadIdx.x;
    if (i < N) rowptr[i] += bsums[blockIdx.x];
    if (i == 0) rowptr[N] = E;
}

// place edges: LDS fill counters per node; writes confined to ~4KB bucket window
__global__ void fillB(const uint2* __restrict__ tmp, const int* __restrict__ boff,
                      const int* __restrict__ rowptr, const float* __restrict__ dinv,
                      float2* __restrict__ ew, int N) {
    __shared__ int lfill[NBNODES];
    __shared__ int rbase[NBNODES];
    __shared__ float ldv[NBNODES];
    int b = blockIdx.x, t = threadIdx.x;
    if (t < NBNODES) {
        lfill[t] = 0;
        int node = b * NBNODES + t;
        rbase[t] = (node < N) ? rowptr[node] : 0;
        ldv[t]   = (node < N) ? dinv[node] : 0.f;
    }
    __syncthreads();
    int p0 = boff[b], p1 = boff[b+1];
    for (int p = p0 + t; p < p1; p += 256) {
        uint2 e = tmp[p];
        int s = (int)e.x, dl = (int)(e.y & (NBNODES-1));
        float w = dinv[s] * ldv[dl];
        int pos = rbase[dl] + atomicAdd(&lfill[dl], 1);
        ew[pos] = make_float2(__int_as_float(s), w);
    }
}

// a1[n] = {S x}[n], .w = dinv^2; 16-lane group per node
__global__ void agg3_wave(const float* __restrict__ x, const float2* __restrict__ ew,
                          const int* __restrict__ rowptr, const float* __restrict__ dinv,
                          float4* __restrict__ a1, int N) {
    int g   = (blockIdx.x * blockDim.x + threadIdx.x) >> 4;
    int sub = threadIdx.x & 15;
    if (g >= N) return;
    int p0 = rowptr[g], p1 = rowptr[g+1];
    float ax = 0.f, ay = 0.f, az = 0.f;
    for (int p = p0 + sub; p < p1; p += 16) {
        float2 e = ew[p];
        int s = __float_as_int(e.x);
        ax = fmaf(e.y, x[s*3+0], ax);
        ay = fmaf(e.y, x[s*3+1], ay);
        az = fmaf(e.y, x[s*3+2], az);
    }
    #pragma unroll
    for (int off = 8; off; off >>= 1) {
        ax += __shfl_down(ax, off, 16);
        ay += __shfl_down(ay, off, 16);
        az += __shfl_down(az, off, 16);
    }
    if (sub == 0) {
        float dv = dinv[g], sw = dv * dv;
        a1[g] = make_float4(fmaf(sw, x[g*3+0], ax),
                            fmaf(sw, x[g*3+1], ay),
                            fmaf(sw, x[g*3+2], az), sw);
    }
}

// wc[k] = W3[k][:] @ Wh; wc[64] = b3 @ Wh + bh
__global__ void fold_head(const float* __restrict__ W3, const float* __restrict__ b3,
                          const float* __restrict__ Wh, const float* __restrict__ bh,
                          float* __restrict__ wc) {
    int k = threadIdx.x;              // 64
    float acc = 0.0f;
    for (int f = 0; f < 64; f++) acc += W3[k*64+f] * Wh[f];
    wc[k] = acc;
    if (k == 0) {
        float bb = bh[0];
        for (int f = 0; f < 64; f++) bb += b3[f] * Wh[f];
        wc[64] = bb;
    }
}

// z[n] = relu( (S relu(a1@W1+b1))[n] @ W2 + b2 ) @ wc
__global__ void fused_l2l3(const float2* __restrict__ ew, const int* __restrict__ rowptr,
                           const float4* __restrict__ a1, const float* __restrict__ W1,
                           const float* __restrict__ b1, const float* __restrict__ W2,
                           const float* __restrict__ b2, const float* __restrict__ wc,
                           float* __restrict__ z, int N) {
    __shared__ float Wl[64*64];
    __shared__ float a2buf[4][64];
    const int tid = threadIdx.x;
    for (int i = tid; i < 4096; i += 256) Wl[i] = W2[i];
    const int lane = tid & 63;
    const int wv   = tid >> 6;
    const float w10 = W1[lane], w11 = W1[64+lane], w12 = W1[128+lane];
    const float b1f = b1[lane], b2f = b2[lane], wcf = wc[lane];
    const int NPW = 8;
    const int n0 = (blockIdx.x * 4 + wv) * NPW;
    int   rpl = rowptr[min(n0 + lane, N)];         // lanes 0..8 used
    float4 sg = a1[min(n0 + lane, N - 1)];         // lanes 0..7 used (self terms)
    __syncthreads();
    for (int cur = 0; cur < NPW; ++cur) {
        int n = n0 + cur;
        if (n >= N) break;
        int p0 = __builtin_amdgcn_readfirstlane(__shfl(rpl, cur));
        int p1 = __builtin_amdgcn_readfirstlane(__shfl(rpl, cur + 1));
        // self-loop term
        float sx = __shfl(sg.x, cur), sy = __shfl(sg.y, cur);
        float sz = __shfl(sg.z, cur), sw = __shfl(sg.w, cur);
        float t = fmaf(sz, w12, fmaf(sy, w11, fmaf(sx, w10, b1f)));
        float acc = sw * fmaxf(t, 0.f);
        for (int pc = p0; pc < p1; pc += 64) {
            int pidx = pc + lane; if (pidx >= p1) pidx = p1 - 1;   // clamp (valid addr)
            float2 e  = ew[pidx];                  // coalesced per-lane
            float4 g  = a1[__float_as_int(e.x)];   // 64-wide gather: true MLP
            int m = p1 - pc; if (m > 64) m = 64;   // uniform trip count
            int j = 0;
            for (; j + 3 < m; j += 4) {            // DYNAMIC trip: ~deg iters, not 64
                #pragma unroll
                for (int u = 0; u < 4; ++u) {
                    float ex = rlane(g.x, j+u), ey = rlane(g.y, j+u);
                    float ez = rlane(g.z, j+u), ww = rlane(e.y, j+u);
                    float tt = fmaf(ez, w12, fmaf(ey, w11, fmaf(ex, w10, b1f)));
                    acc = fmaf(ww, fmaxf(tt, 0.f), acc);
                }
            }
            for (; j < m; ++j) {
                float ex = rlane(g.x, j), ey = rlane(g.y, j);
                float ez = rlane(g.z, j), ww = rlane(e.y, j);
                float tt = fmaf(ez, w12, fmaf(ey, w11, fmaf(ex, w10, b1f)));
                acc = fmaf(ww, fmaxf(tt, 0.f), acc);
            }
        }
        // a2 exchange (wave-private LDS row), then W2 matmul from LDS
        a2buf[wv][lane] = acc;
        float h = b2f;
        const float4* a4 = (const float4*)a2buf[wv];
        #pragma unroll
        for (int k4 = 0; k4 < 16; ++k4) {
            float4 a = a4[k4];                     // uniform broadcast read
            h = fmaf(a.x, Wl[(4*k4+0)*64 + lane], h);
            h = fmaf(a.y, Wl[(4*k4+1)*64 + lane], h);
            h = fmaf(a.z, Wl[(4*k4+2)*64 + lane], h);
            h = fmaf(a.w, Wl[(4*k4+3)*64 + lane], h);
        }
        float v = fmaxf(h, 0.f) * wcf;
        #pragma unroll
        for (int off = 32; off; off >>= 1) v += __shfl_down(v, off);
        if (lane == 0) z[n] = v;
    }
}

// logits[n] = dinv^2 z[n] + sum_e w z[s] + c; 16-lane group per node
__global__ void final_wave(const float* __restrict__ z, const float2* __restrict__ ew,
                           const int* __restrict__ rowptr, const float* __restrict__ dinv,
                           const float* __restrict__ wc, float* __restrict__ out, int N) {
    int g   = (blockIdx.x * blockDim.x + threadIdx.x) >> 4;
    int sub = threadIdx.x & 15;
    if (g >= N) return;
    int p0 = rowptr[g], p1 = rowptr[g+1];
    float acc = 0.f;
    for (int p = p0 + sub; p < p1; p += 16) {
        float2 e = ew[p];
        acc = fmaf(e.y, z[__float_as_int(e.x)], acc);
    }
    #pragma unroll
    for (int off = 8; off; off >>= 1) acc += __shfl_down(acc, off, 16);
    if (sub == 0) {
        float dv = dinv[g];
        out[g] = fmaf(dv * dv, z[g], acc) + wc[64];
    }
}

extern "C" void kernel_launch(void* const* d_in, const int* in_sizes, int n_in,
                              void* d_out, int out_size, void* d_ws, size_t ws_size,
                              hipStream_t stream) {
    const float* x   = (const float*)d_in[0];
    const int*   ei  = (const int*)d_in[1];
    const float* W1  = (const float*)d_in[2];
    const float* b1  = (const float*)d_in[3];
    const float* W2  = (const float*)d_in[4];
    const float* b2  = (const float*)d_in[5];
    const float* W3  = (const float*)d_in[6];
    const float* b3  = (const float*)d_in[7];
    const float* Wh  = (const float*)d_in[8];
    const float* bh  = (const float*)d_in[9];
    float* logits = (float*)d_out;

    const int N = in_sizes[0] / 3;
    const int E = in_sizes[1] / 2;
    const int* src = ei;
    const int* dst = ei + E;
    const int B = (N + NBNODES - 1) >> NBSHIFT;   // 3125 buckets

    float* base = (float*)d_ws;
    size_t o = 0;
    float*  dinv   = base + o; o += (size_t)N;
    o = (o + 3) & ~(size_t)3;
    float4* a1     = (float4*)(base + o); o += (size_t)4*N;
    int*    rowptr = (int*)(base + o); o += (size_t)N + 1;
    int*    bsums  = (int*)(base + o); o += 1024;
    o = (o + 1) & ~(size_t)1;
    float2* ew     = (float2*)(base + o); o += (size_t)2*E;
    uint2*  tmpb   = (uint2*)(base + o); o += (size_t)2*E;
    float*  zbuf   = base + o; o += (size_t)N;
    float*  wc     = base + o; o += 65;
    int*    cnt    = (int*)(base + o); o += (size_t)N;
    int*    bcnt_  = (int*)(base + o); o += (size_t)B;    // bcnt|bfill contiguous
    int*    bfill  = (int*)(base + o); o += (size_t)B;
    int*    boff   = (int*)(base + o); o += (size_t)B + 1;

    const int BS = 256;
    int gE  = (E + BS - 1) / BS;
    int gN  = (N + BS - 1) / BS;
    int g16 = ((size_t)N * 16 + BS - 1) / BS;   // 16-lane group per node
    int gFU = (N + 31) / 32;                    // 4 waves x 8 nodes per block

    hipMemsetAsync(bcnt_, 0, (size_t)2 * B * sizeof(int), stream);

    bcount   <<<gE, BS, 0, stream>>>(dst, bcnt_, E);
    bscan    <<<1, 1024, 0, stream>>>(bcnt_, boff, B);
    bappend  <<<gE, BS, 0, stream>>>(src, dst, boff, bfill, tmpb, E);
    countB   <<<B,  BS, 0, stream>>>(tmpb, boff, cnt, N);
    scan1    <<<gN, BS, 0, stream>>>(cnt, rowptr, bsums, dinv, N);
    scan2    <<<1, 1024, 0, stream>>>(bsums, gN);
    scan3    <<<gN, BS, 0, stream>>>(rowptr, bsums, N, E);
    fillB    <<<B,  BS, 0, stream>>>(tmpb, boff, rowptr, dinv, ew, N);

    agg3_wave  <<<g16, BS, 0, stream>>>(x, ew, rowptr, dinv, a1, N);
    fold_head  <<<1, 64, 0, stream>>>(W3, b3, Wh, bh, wc);
    fused_l2l3 <<<gFU, BS, 0, stream>>>(ew, rowptr, a1, W1, b1, W2, b2, wc, zbuf, N);
    final_wave <<<g16, BS, 0, stream>>>(zbuf, ew, rowptr, dinv, wc, logits, N);
}

// Round 9
// 253.703 us; speedup vs baseline: 2.8193x; 2.8193x over previous
//
#include <hip/hip_runtime.h>

// GCN 3-layer, R9 = R8 with the nontemporal-store type fixed (ext_vector_type).
//  a1 = S x  (float4 {Sx.xyz, dinv^2}), 16-lane-group per node.
//  fused_l2l3: wave per 8 nodes, lane=feature; per 64-edge chunk ONE coalesced
//    ew load + ONE per-lane a1[src] gather, then dynamic-trip readlane loop.
//  logits = S z + c, 16-lane group per node.
// ws floats: dinv[N] | a1[4N] | rowptr[N+1] | bsums[1024] | ew[2E] | z[N] | wc[65] | cnt[N]|fill[N]

typedef float vfloat2 __attribute__((ext_vector_type(2)));

__device__ __forceinline__ float rlane(float v, int l) {
    return __int_as_float(__builtin_amdgcn_readlane(__float_as_int(v), l));
}

__global__ void count_deg(const int* __restrict__ dst, int* __restrict__ cnt, int E) {
    int e = blockIdx.x * blockDim.x + threadIdx.x;
    if (e < E) atomicAdd(&cnt[dst[e]], 1);
}

// exclusive scan phase 1 (+ dinv fused)
__global__ void scan1(const int* __restrict__ cnt, int* __restrict__ rowptr,
                      int* __restrict__ bsums, float* __restrict__ dinv, int N) {
    __shared__ int tmp[256];
    int i = blockIdx.x * 256 + threadIdx.x;
    int v = (i < N) ? cnt[i] : 0;
    if (i < N) dinv[i] = rsqrtf((float)(v + 1));
    tmp[threadIdx.x] = v; __syncthreads();
    for (int off = 1; off < 256; off <<= 1) {
        int t = (threadIdx.x >= off) ? tmp[threadIdx.x - off] : 0;
        __syncthreads();
        tmp[threadIdx.x] += t;
        __syncthreads();
    }
    if (i < N) rowptr[i] = tmp[threadIdx.x] - v;
    if (threadIdx.x == 255) bsums[blockIdx.x] = tmp[255];
}

__global__ void scan2(int* __restrict__ bsums, int nb) {    // 1 block, 1024 thr
    __shared__ int tmp[1024];
    int v = (threadIdx.x < nb) ? bsums[threadIdx.x] : 0;
    tmp[threadIdx.x] = v; __syncthreads();
    for (int off = 1; off < 1024; off <<= 1) {
        int t = (threadIdx.x >= off) ? tmp[threadIdx.x - off] : 0;
        __syncthreads();
        tmp[threadIdx.x] += t;
        __syncthreads();
    }
    if (threadIdx.x < nb) bsums[threadIdx.x] = tmp[threadIdx.x] - v;
}

__global__ void scan3(int* __restrict__ rowptr, const int* __restrict__ bsums, int N, int E) {
    int i = blockIdx.x * 256 + threadIdx.x;
    if (i < N) rowptr[i] += bsums[blockIdx.x];
    if (i == 0) rowptr[N] = E;
}

__global__ void csr_fill(const int* __restrict__ src, const int* __restrict__ dst,
                         const float* __restrict__ dinv, const int* __restrict__ rowptr,
                         int* __restrict__ fill, float2* __restrict__ ew, int E) {
    int e = blockIdx.x * blockDim.x + threadIdx.x;
    if (e >= E) return;
    int s = src[e], d = dst[e];
    int p = rowptr[d] + atomicAdd(&fill[d], 1);
    vfloat2 v; v.x = __int_as_float(s); v.y = dinv[s] * dinv[d];
    __builtin_nontemporal_store(v, (vfloat2*)&ew[p]);   // bypass L2 partial-line thrash
}

// a1[n] = {S x}[n], .w = dinv^2; 16-lane group per node
__global__ void agg3_wave(const float* __restrict__ x, const float2* __restrict__ ew,
                          const int* __restrict__ rowptr, const float* __restrict__ dinv,
                          float4* __restrict__ a1, int N) {
    int g   = (blockIdx.x * blockDim.x + threadIdx.x) >> 4;
    int sub = threadIdx.x & 15;
    if (g >= N) return;
    int p0 = rowptr[g], p1 = rowptr[g+1];
    float ax = 0.f, ay = 0.f, az = 0.f;
    for (int p = p0 + sub; p < p1; p += 16) {
        float2 e = ew[p];
        int s = __float_as_int(e.x);
        ax = fmaf(e.y, x[s*3+0], ax);
        ay = fmaf(e.y, x[s*3+1], ay);
        az = fmaf(e.y, x[s*3+2], az);
    }
    #pragma unroll
    for (int off = 8; off; off >>= 1) {
        ax += __shfl_down(ax, off, 16);
        ay += __shfl_down(ay, off, 16);
        az += __shfl_down(az, off, 16);
    }
    if (sub == 0) {
        float dv = dinv[g], sw = dv * dv;
        a1[g] = make_float4(fmaf(sw, x[g*3+0], ax),
                            fmaf(sw, x[g*3+1], ay),
                            fmaf(sw, x[g*3+2], az), sw);
    }
}

// wc[k] = W3[k][:] @ Wh; wc[64] = b3 @ Wh + bh
__global__ void fold_head(const float* __restrict__ W3, const float* __restrict__ b3,
                          const float* __restrict__ Wh, const float* __restrict__ bh,
                          float* __restrict__ wc) {
    int k = threadIdx.x;              // 64
    float acc = 0.0f;
    for (int f = 0; f < 64; f++) acc += W3[k*64+f] * Wh[f];
    wc[k] = acc;
    if (k == 0) {
        float bb = bh[0];
        for (int f = 0; f < 64; f++) bb += b3[f] * Wh[f];
        wc[64] = bb;
    }
}

// z[n] = relu( (S relu(a1@W1+b1))[n] @ W2 + b2 ) @ wc
__global__ void fused_l2l3(const float2* __restrict__ ew, const int* __restrict__ rowptr,
                           const float4* __restrict__ a1, const float* __restrict__ W1,
                           const float* __restrict__ b1, const float* __restrict__ W2,
                           const float* __restrict__ b2, const float* __restrict__ wc,
                           float* __restrict__ z, int N) {
    __shared__ float Wl[64*64];
    __shared__ float a2buf[4][64];
    const int tid = threadIdx.x;
    for (int i = tid; i < 4096; i += 256) Wl[i] = W2[i];
    const int lane = tid & 63;
    const int wv   = tid >> 6;
    const float w10 = W1[lane], w11 = W1[64+lane], w12 = W1[128+lane];
    const float b1f = b1[lane], b2f = b2[lane], wcf = wc[lane];
    const int NPW = 8;
    const int n0 = (blockIdx.x * 4 + wv) * NPW;
    int   rpl = rowptr[min(n0 + lane, N)];         // lanes 0..8 used
    float4 sg = a1[min(n0 + lane, N - 1)];         // lanes 0..7 used (self terms)
    __syncthreads();
    for (int cur = 0; cur < NPW; ++cur) {
        int n = n0 + cur;
        if (n >= N) break;
        int p0 = __builtin_amdgcn_readfirstlane(__shfl(rpl, cur));
        int p1 = __builtin_amdgcn_readfirstlane(__shfl(rpl, cur + 1));
        // self-loop term
        float sx = __shfl(sg.x, cur), sy = __shfl(sg.y, cur);
        float sz = __shfl(sg.z, cur), sw = __shfl(sg.w, cur);
        float t = fmaf(sz, w12, fmaf(sy, w11, fmaf(sx, w10, b1f)));
        float acc = sw * fmaxf(t, 0.f);
        for (int pc = p0; pc < p1; pc += 64) {
            int pidx = pc + lane; if (pidx >= p1) pidx = p1 - 1;   // clamp (valid addr)
            float2 e  = ew[pidx];                  // coalesced per-lane
            float4 g  = a1[__float_as_int(e.x)];   // 64-wide gather: true MLP
            int m = p1 - pc; if (m > 64) m = 64;   // uniform trip count (SGPR)
            int j = 0;
            for (; j + 3 < m; j += 4) {            // dynamic trip: ~deg iters, not 64
                #pragma unroll
                for (int u = 0; u < 4; ++u) {
                    float ex = rlane(g.x, j+u), ey = rlane(g.y, j+u);
                    float ez = rlane(g.z, j+u), ww = rlane(e.y, j+u);
                    float tt = fmaf(ez, w12, fmaf(ey, w11, fmaf(ex, w10, b1f)));
                    acc = fmaf(ww, fmaxf(tt, 0.f), acc);
                }
            }
            for (; j < m; ++j) {
                float ex = rlane(g.x, j), ey = rlane(g.y, j);
                float ez = rlane(g.z, j), ww = rlane(e.y, j);
                float tt = fmaf(ez, w12, fmaf(ey, w11, fmaf(ex, w10, b1f)));
                acc = fmaf(ww, fmaxf(tt, 0.f), acc);
            }
        }
        // a2 exchange (wave-private LDS row), then W2 matmul from LDS
        a2buf[wv][lane] = acc;
        float h = b2f;
        const float4* a4 = (const float4*)a2buf[wv];
        #pragma unroll
        for (int k4 = 0; k4 < 16; ++k4) {
            float4 a = a4[k4];                     // uniform broadcast read
            h = fmaf(a.x, Wl[(4*k4+0)*64 + lane], h);
            h = fmaf(a.y, Wl[(4*k4+1)*64 + lane], h);
            h = fmaf(a.z, Wl[(4*k4+2)*64 + lane], h);
            h = fmaf(a.w, Wl[(4*k4+3)*64 + lane], h);
        }
        float v = fmaxf(h, 0.f) * wcf;
        #pragma unroll
        for (int off = 32; off; off >>= 1) v += __shfl_down(v, off);
        if (lane == 0) z[n] = v;
    }
}

// logits[n] = dinv^2 z[n] + sum_e w z[s] + c; 16-lane group per node
__global__ void final_wave(const float* __restrict__ z, const float2* __restrict__ ew,
                           const int* __restrict__ rowptr, const float* __restrict__ dinv,
                           const float* __restrict__ wc, float* __restrict__ out, int N) {
    int g   = (blockIdx.x * blockDim.x + threadIdx.x) >> 4;
    int sub = threadIdx.x & 15;
    if (g >= N) return;
    int p0 = rowptr[g], p1 = rowptr[g+1];
    float acc = 0.f;
    for (int p = p0 + sub; p < p1; p += 16) {
        float2 e = ew[p];
        acc = fmaf(e.y, z[__float_as_int(e.x)], acc);
    }
    #pragma unroll
    for (int off = 8; off; off >>= 1) acc += __shfl_down(acc, off, 16);
    if (sub == 0) {
        float dv = dinv[g];
        out[g] = fmaf(dv * dv, z[g], acc) + wc[64];
    }
}

extern "C" void kernel_launch(void* const* d_in, const int* in_sizes, int n_in,
                              void* d_out, int out_size, void* d_ws, size_t ws_size,
                              hipStream_t stream) {
    const float* x   = (const float*)d_in[0];
    const int*   ei  = (const int*)d_in[1];
    const float* W1  = (const float*)d_in[2];
    const float* b1  = (const float*)d_in[3];
    const float* W2  = (const float*)d_in[4];
    const float* b2  = (const float*)d_in[5];
    const float* W3  = (const float*)d_in[6];
    const float* b3  = (const float*)d_in[7];
    const float* Wh  = (const float*)d_in[8];
    const float* bh  = (const float*)d_in[9];
    float* logits = (float*)d_out;

    const int N = in_sizes[0] / 3;
    const int E = in_sizes[1] / 2;
    const int* src = ei;
    const int* dst = ei + E;

    float* base = (float*)d_ws;
    size_t o = 0;
    float*  dinv   = base + o; o += (size_t)N;
    o = (o + 3) & ~(size_t)3;
    float4* a1     = (float4*)(base + o); o += (size_t)4*N;
    int*    rowptr = (int*)(base + o); o += (size_t)N + 1;
    int*    bsums  = (int*)(base + o); o += 1024;
    o = (o + 1) & ~(size_t)1;
    float2* ew     = (float2*)(base + o); o += (size_t)2*E;
    float*  zbuf   = base + o; o += (size_t)N;
    float*  wc     = base + o; o += 65;
    int*    cnt    = (int*)(base + o); o += (size_t)N;   // cnt|fill contiguous
    int*    fill   = (int*)(base + o); o += (size_t)N;

    const int BS = 256;
    int gE  = (E + BS - 1) / BS;
    int gN  = (N + BS - 1) / BS;
    int g16 = ((size_t)N * 16 + BS - 1) / BS;   // 16-lane group per node
    int gFU = (N + 31) / 32;                    // 4 waves x 8 nodes per block

    (void)hipMemsetAsync(cnt, 0, (size_t)2 * N * sizeof(int), stream);

    count_deg   <<<gE, BS, 0, stream>>>(dst, cnt, E);
    scan1       <<<gN, BS, 0, stream>>>(cnt, rowptr, bsums, dinv, N);
    scan2       <<<1, 1024, 0, stream>>>(bsums, gN);
    scan3       <<<gN, BS, 0, stream>>>(rowptr, bsums, N, E);
    csr_fill    <<<gE, BS, 0, stream>>>(src, dst, dinv, rowptr, fill, ew, E);

    agg3_wave   <<<g16, BS, 0, stream>>>(x, ew, rowptr, dinv, a1, N);
    fold_head   <<<1, 64, 0, stream>>>(W3, b3, Wh, bh, wc);
    fused_l2l3  <<<gFU, BS, 0, stream>>>(ew, rowptr, a1, W1, b1, W2, b2, wc, zbuf, N);
    final_wave  <<<g16, BS, 0, stream>>>(zbuf, ew, rowptr, dinv, wc, logits, N);
}

// Round 10
// 169.377 us; speedup vs baseline: 4.2229x; 1.4979x over previous
//
#include <hip/hip_runtime.h>

// GCN 3-layer, R10: contention-free two-level counting sort for CSR build.
//  bhist -> gscan(ghist[bucket][block]) -> bscatter(tmp {src,dst}) ->
//  countB (dense cnt) -> scan(rowptr+dinv) -> fillB (dense ew write + fused agg3).
//  fused_l2l3: wave per 8 nodes, lane=feature; dynamic-trip readlane loop (R9).
//  logits = S z + c, 16-lane group per node.
// Bucket = 256 consecutive dst nodes. No global atomics anywhere in the build
// except LDS-local ones. No memsets.

#define BKSH 8                      // 256 nodes per bucket
#define EPB  4096                   // edges per scatter block (256 thr x 16)

typedef float vfloat2 __attribute__((ext_vector_type(2)));

__device__ __forceinline__ float rlane(float v, int l) {
    return __int_as_float(__builtin_amdgcn_readlane(__float_as_int(v), l));
}

// ---- per-block bucket histogram: ghist[bucket*BLK + blk] (dense write) ----
__global__ void bhist(const int* __restrict__ dst, int* __restrict__ ghist,
                      int E, int NBK, int BLK) {
    __shared__ int h[512];
    int t = threadIdx.x, b = blockIdx.x;
    for (int i = t; i < NBK; i += 256) h[i] = 0;
    __syncthreads();
    int base = b * EPB;
    #pragma unroll
    for (int i = 0; i < 16; ++i) {
        int e = base + i * 256 + t;
        if (e < E) atomicAdd(&h[dst[e] >> BKSH], 1);
    }
    __syncthreads();
    for (int i = t; i < NBK; i += 256) ghist[(size_t)i * BLK + b] = h[i];
}

// ---- generic exclusive scan (3 phases) ----
__global__ void gscan1(const int* __restrict__ in, int* __restrict__ out,
                       int* __restrict__ bsums, int M) {
    __shared__ int tmp[256];
    int i = blockIdx.x * 256 + threadIdx.x;
    int v = (i < M) ? in[i] : 0;
    tmp[threadIdx.x] = v; __syncthreads();
    for (int off = 1; off < 256; off <<= 1) {
        int t = (threadIdx.x >= off) ? tmp[threadIdx.x - off] : 0;
        __syncthreads();
        tmp[threadIdx.x] += t;
        __syncthreads();
    }
    if (i < M) out[i] = tmp[threadIdx.x] - v;
    if (threadIdx.x == 255) bsums[blockIdx.x] = tmp[255];
}

__global__ void gscan2(int* __restrict__ bsums, int nb) {   // 1 block, 1024 thr
    __shared__ int tmp[1024];
    int v = (threadIdx.x < nb) ? bsums[threadIdx.x] : 0;
    tmp[threadIdx.x] = v; __syncthreads();
    for (int off = 1; off < 1024; off <<= 1) {
        int t = (threadIdx.x >= off) ? tmp[threadIdx.x - off] : 0;
        __syncthreads();
        tmp[threadIdx.x] += t;
        __syncthreads();
    }
    if (threadIdx.x < nb) bsums[threadIdx.x] = tmp[threadIdx.x] - v;
}

__global__ void gscan3(int* __restrict__ out, const int* __restrict__ bsums, int M) {
    int i = blockIdx.x * 256 + threadIdx.x;
    if (i < M) out[i] += bsums[blockIdx.x];
}

// ---- scatter edges into bucket-sorted tmp using precomputed offsets ----
__global__ void bscatter(const int* __restrict__ src, const int* __restrict__ dst,
                         const int* __restrict__ goff, uint2* __restrict__ tmp,
                         int E, int NBK, int BLK) {
    __shared__ int off[512];
    int t = threadIdx.x, b = blockIdx.x;
    for (int i = t; i < NBK; i += 256) off[i] = goff[(size_t)i * BLK + b];
    __syncthreads();
    int base = b * EPB;
    #pragma unroll
    for (int i = 0; i < 16; ++i) {
        int e = base + i * 256 + t;
        if (e < E) {
            int d = dst[e];
            int p = atomicAdd(&off[d >> BKSH], 1);   // LDS-local, ~10/bin
            tmp[p] = make_uint2((unsigned)src[e], (unsigned)d);
        }
    }
}

// ---- per-node degree from bucket-local tmp chunk (dense cnt write) ----
__global__ void countB(const uint2* __restrict__ tmp, const int* __restrict__ goff,
                       int* __restrict__ cnt, int N, int NBK, int BLK, int E) {
    __shared__ int lc[256];
    int b = blockIdx.x, t = threadIdx.x;
    lc[t] = 0; __syncthreads();
    int p0 = goff[(size_t)b * BLK];
    int p1 = (b + 1 < NBK) ? goff[(size_t)(b + 1) * BLK] : E;
    for (int p = p0 + t; p < p1; p += 256) atomicAdd(&lc[tmp[p].y & 255], 1);
    __syncthreads();
    int node = (b << BKSH) + t;
    if (node < N) cnt[node] = lc[t];
}

// ---- node scan phase 1 (+ dinv fused) ----
__global__ void scan1(const int* __restrict__ cnt, int* __restrict__ rowptr,
                      int* __restrict__ bsums, float* __restrict__ dinv, int N) {
    __shared__ int tmp[256];
    int i = blockIdx.x * 256 + threadIdx.x;
    int v = (i < N) ? cnt[i] : 0;
    if (i < N) dinv[i] = rsqrtf((float)(v + 1));
    tmp[threadIdx.x] = v; __syncthreads();
    for (int off = 1; off < 256; off <<= 1) {
        int t = (threadIdx.x >= off) ? tmp[threadIdx.x - off] : 0;
        __syncthreads();
        tmp[threadIdx.x] += t;
        __syncthreads();
    }
    if (i < N) rowptr[i] = tmp[threadIdx.x] - v;
    if (threadIdx.x == 255) bsums[blockIdx.x] = tmp[255];
}

__global__ void scan3(int* __restrict__ rowptr, const int* __restrict__ bsums, int N, int E) {
    int i = blockIdx.x * 256 + threadIdx.x;
    if (i < N) rowptr[i] += bsums[blockIdx.x];
    if (i == 0) rowptr[N] = E;
}

// ---- place edges (dense 32KB window) + fused layer-1 aggregation ----
__global__ void fillB(const uint2* __restrict__ tmp, const int* __restrict__ goff,
                      const int* __restrict__ rowptr, const float* __restrict__ dinv,
                      const float* __restrict__ x, float2* __restrict__ ew,
                      float4* __restrict__ a1, int N, int NBK, int BLK, int E) {
    __shared__ int   lfill[256];
    __shared__ int   rbase[257];
    __shared__ float ldv[256];
    int b = blockIdx.x, t = threadIdx.x;
    int node0 = b << BKSH;
    lfill[t] = 0;
    int node = node0 + t;
    rbase[t] = rowptr[min(node, N)];
    ldv[t]   = dinv[min(node, N - 1)];
    if (t == 0) rbase[256] = rowptr[min(node0 + 256, N)];
    __syncthreads();
    int p0 = goff[(size_t)b * BLK];
    int p1 = (b + 1 < NBK) ? goff[(size_t)(b + 1) * BLK] : E;
    for (int p = p0 + t; p < p1; p += 256) {
        uint2 e = tmp[p];
        int s = (int)e.x, dl = (int)(e.y & 255);
        float w = dinv[s] * ldv[dl];
        int pos = rbase[dl] + atomicAdd(&lfill[dl], 1);
        ew[pos] = make_float2(__int_as_float(s), w);
    }
    __syncthreads();
    // fused agg3: 16 lane-groups sweep the bucket's 256 nodes (ew is L2-hot)
    int grp = t >> 4, sub = t & 15;
    for (int ni = grp; ni < 256; ni += 16) {
        int n = node0 + ni;
        if (n >= N) break;
        int q0 = rbase[ni], q1 = rbase[ni + 1];
        float ax = 0.f, ay = 0.f, az = 0.f;
        for (int p = q0 + sub; p < q1; p += 16) {
            float2 e = ew[p];
            int s = __float_as_int(e.x);
            ax = fmaf(e.y, x[s*3+0], ax);
            ay = fmaf(e.y, x[s*3+1], ay);
            az = fmaf(e.y, x[s*3+2], az);
        }
        #pragma unroll
        for (int off = 8; off; off >>= 1) {
            ax += __shfl_down(ax, off, 16);
            ay += __shfl_down(ay, off, 16);
            az += __shfl_down(az, off, 16);
        }
        if (sub == 0) {
            float dv = ldv[ni], sw = dv * dv;
            a1[n] = make_float4(fmaf(sw, x[n*3+0], ax),
                                fmaf(sw, x[n*3+1], ay),
                                fmaf(sw, x[n*3+2], az), sw);
        }
    }
}

// wc[k] = W3[k][:] @ Wh; wc[64] = b3 @ Wh + bh
__global__ void fold_head(const float* __restrict__ W3, const float* __restrict__ b3,
                          const float* __restrict__ Wh, const float* __restrict__ bh,
                          float* __restrict__ wc) {
    int k = threadIdx.x;              // 64
    float acc = 0.0f;
    for (int f = 0; f < 64; f++) acc += W3[k*64+f] * Wh[f];
    wc[k] = acc;
    if (k == 0) {
        float bb = bh[0];
        for (int f = 0; f < 64; f++) bb += b3[f] * Wh[f];
        wc[64] = bb;
    }
}

// z[n] = relu( (S relu(a1@W1+b1))[n] @ W2 + b2 ) @ wc
__global__ void fused_l2l3(const float2* __restrict__ ew, const int* __restrict__ rowptr,
                           const float4* __restrict__ a1, const float* __restrict__ W1,
                           const float* __restrict__ b1, const float* __restrict__ W2,
                           const float* __restrict__ b2, const float* __restrict__ wc,
                           float* __restrict__ z, int N) {
    __shared__ float Wl[64*64];
    __shared__ float a2buf[4][64];
    const int tid = threadIdx.x;
    for (int i = tid; i < 4096; i += 256) Wl[i] = W2[i];
    const int lane = tid & 63;
    const int wv   = tid >> 6;
    const float w10 = W1[lane], w11 = W1[64+lane], w12 = W1[128+lane];
    const float b1f = b1[lane], b2f = b2[lane], wcf = wc[lane];
    const int NPW = 8;
    const int n0 = (blockIdx.x * 4 + wv) * NPW;
    int   rpl = rowptr[min(n0 + lane, N)];         // lanes 0..8 used
    float4 sg = a1[min(n0 + lane, N - 1)];         // lanes 0..7 used (self terms)
    __syncthreads();
    for (int cur = 0; cur < NPW; ++cur) {
        int n = n0 + cur;
        if (n >= N) break;
        int p0 = __builtin_amdgcn_readfirstlane(__shfl(rpl, cur));
        int p1 = __builtin_amdgcn_readfirstlane(__shfl(rpl, cur + 1));
        float sx = __shfl(sg.x, cur), sy = __shfl(sg.y, cur);
        float sz = __shfl(sg.z, cur), sw = __shfl(sg.w, cur);
        float t = fmaf(sz, w12, fmaf(sy, w11, fmaf(sx, w10, b1f)));
        float acc = sw * fmaxf(t, 0.f);
        for (int pc = p0; pc < p1; pc += 64) {
            int pidx = pc + lane; if (pidx >= p1) pidx = p1 - 1;
            float2 e  = ew[pidx];                  // coalesced per-lane
            float4 g  = a1[__float_as_int(e.x)];   // 64-wide gather
            int m = p1 - pc; if (m > 64) m = 64;   // uniform trip (SGPR)
            int j = 0;
            for (; j + 3 < m; j += 4) {
                #pragma unroll
                for (int u = 0; u < 4; ++u) {
                    float ex = rlane(g.x, j+u), ey = rlane(g.y, j+u);
                    float ez = rlane(g.z, j+u), ww = rlane(e.y, j+u);
                    float tt = fmaf(ez, w12, fmaf(ey, w11, fmaf(ex, w10, b1f)));
                    acc = fmaf(ww, fmaxf(tt, 0.f), acc);
                }
            }
            for (; j < m; ++j) {
                float ex = rlane(g.x, j), ey = rlane(g.y, j);
                float ez = rlane(g.z, j), ww = rlane(e.y, j);
                float tt = fmaf(ez, w12, fmaf(ey, w11, fmaf(ex, w10, b1f)));
                acc = fmaf(ww, fmaxf(tt, 0.f), acc);
            }
        }
        a2buf[wv][lane] = acc;
        float h = b2f;
        const float4* a4 = (const float4*)a2buf[wv];
        #pragma unroll
        for (int k4 = 0; k4 < 16; ++k4) {
            float4 a = a4[k4];
            h = fmaf(a.x, Wl[(4*k4+0)*64 + lane], h);
            h = fmaf(a.y, Wl[(4*k4+1)*64 + lane], h);
            h = fmaf(a.z, Wl[(4*k4+2)*64 + lane], h);
            h = fmaf(a.w, Wl[(4*k4+3)*64 + lane], h);
        }
        float v = fmaxf(h, 0.f) * wcf;
        #pragma unroll
        for (int off = 32; off; off >>= 1) v += __shfl_down(v, off);
        if (lane == 0) z[n] = v;
    }
}

// logits[n] = dinv^2 z[n] + sum_e w z[s] + c; 16-lane group per node
__global__ void final_wave(const float* __restrict__ z, const float2* __restrict__ ew,
                           const int* __restrict__ rowptr, const float* __restrict__ dinv,
                           const float* __restrict__ wc, float* __restrict__ out, int N) {
    int g   = (blockIdx.x * blockDim.x + threadIdx.x) >> 4;
    int sub = threadIdx.x & 15;
    if (g >= N) return;
    int p0 = rowptr[g], p1 = rowptr[g+1];
    float acc = 0.f;
    for (int p = p0 + sub; p < p1; p += 16) {
        float2 e = ew[p];
        acc = fmaf(e.y, z[__float_as_int(e.x)], acc);
    }
    #pragma unroll
    for (int off = 8; off; off >>= 1) acc += __shfl_down(acc, off, 16);
    if (sub == 0) {
        float dv = dinv[g];
        out[g] = fmaf(dv * dv, z[g], acc) + wc[64];
    }
}

extern "C" void kernel_launch(void* const* d_in, const int* in_sizes, int n_in,
                              void* d_out, int out_size, void* d_ws, size_t ws_size,
                              hipStream_t stream) {
    const float* x   = (const float*)d_in[0];
    const int*   ei  = (const int*)d_in[1];
    const float* W1  = (const float*)d_in[2];
    const float* b1  = (const float*)d_in[3];
    const float* W2  = (const float*)d_in[4];
    const float* b2  = (const float*)d_in[5];
    const float* W3  = (const float*)d_in[6];
    const float* b3  = (const float*)d_in[7];
    const float* Wh  = (const float*)d_in[8];
    const float* bh  = (const float*)d_in[9];
    float* logits = (float*)d_out;

    const int N = in_sizes[0] / 3;
    const int E = in_sizes[1] / 2;
    const int* src = ei;
    const int* dst = ei + E;

    const int NBK = (N + 255) >> BKSH;            // 391 buckets
    const int BLK = (E + EPB - 1) / EPB;          // 391 scatter blocks
    const int M   = NBK * BLK;                    // ghist entries

    float* base = (float*)d_ws;
    size_t o = 0;
    float*  dinv   = base + o; o += (size_t)N;
    o = (o + 3) & ~(size_t)3;
    float4* a1     = (float4*)(base + o); o += (size_t)4*N;
    int*    rowptr = (int*)(base + o); o += (size_t)N + 1;
    int*    bsums  = (int*)(base + o); o += 1024;
    int*    gbsums = (int*)(base + o); o += 1024;
    o = (o + 1) & ~(size_t)1;
    float2* ew     = (float2*)(base + o); o += (size_t)2*E;
    uint2*  tmpb   = (uint2*)(base + o); o += (size_t)2*E;
    float*  zbuf   = base + o; o += (size_t)N;
    float*  wc     = base + o; o += 65;
    int*    cnt    = (int*)(base + o); o += (size_t)N;
    int*    ghist  = (int*)(base + o); o += (size_t)M;
    int*    goff   = (int*)(base + o); o += (size_t)M;

    const int BS = 256;
    int gN   = (N + BS - 1) / BS;
    int gM   = (M + BS - 1) / BS;
    int g16  = ((size_t)N * 16 + BS - 1) / BS;
    int gFU  = (N + 31) / 32;

    bhist    <<<BLK, BS, 0, stream>>>(dst, ghist, E, NBK, BLK);
    gscan1   <<<gM,  BS, 0, stream>>>(ghist, goff, gbsums, M);
    gscan2   <<<1, 1024, 0, stream>>>(gbsums, gM);
    gscan3   <<<gM,  BS, 0, stream>>>(goff, gbsums, M);
    bscatter <<<BLK, BS, 0, stream>>>(src, dst, goff, tmpb, E, NBK, BLK);
    countB   <<<NBK, BS, 0, stream>>>(tmpb, goff, cnt, N, NBK, BLK, E);
    scan1    <<<gN,  BS, 0, stream>>>(cnt, rowptr, bsums, dinv, N);
    gscan2   <<<1, 1024, 0, stream>>>(bsums, gN);
    scan3    <<<gN,  BS, 0, stream>>>(rowptr, bsums, N, E);
    fillB    <<<NBK, BS, 0, stream>>>(tmpb, goff, rowptr, dinv, x, ew, a1, N, NBK, BLK, E);

    fold_head  <<<1, 64, 0, stream>>>(W3, b3, Wh, bh, wc);
    fused_l2l3 <<<gFU, BS, 0, stream>>>(ew, rowptr, a1, W1, b1, W2, b2, wc, zbuf, N);
    final_wave <<<g16, BS, 0, stream>>>(zbuf, ew, rowptr, dinv, wc, logits, N);
}

// Round 11
// 160.853 us; speedup vs baseline: 4.4466x; 1.0530x over previous
//
#include <hip/hip_runtime.h>

// GCN 3-layer, R11.
//  Build: bhist -> gscan1/2 (gscan3 folded into readers) -> bscatter ->
//         bucketA (count + LDS-scan -> rowptr+dinv, 1 kernel) -> fillB (+agg3).
//  fused_l2l3: wave per 8 nodes, lane=feature, dynamic-trip readlane loop,
//              cross-node prefetch pipeline (ew early, a1 gather mid-loop).
//  logits = S z + c, 16-lane group per node.

#define BKSH 8                      // 256 nodes per bucket
#define EPB  4096                   // edges per scatter block

__device__ __forceinline__ float rlane(float v, int l) {
    return __int_as_float(__builtin_amdgcn_readlane(__float_as_int(v), l));
}
__device__ __forceinline__ int rfl(int v) { return __builtin_amdgcn_readfirstlane(v); }

// ---- per-block bucket histogram ----
__global__ void bhist(const int* __restrict__ dst, int* __restrict__ ghist,
                      int E, int NBK, int BLK) {
    __shared__ int h[512];
    int t = threadIdx.x, b = blockIdx.x;
    for (int i = t; i < NBK; i += 256) h[i] = 0;
    __syncthreads();
    int base = b * EPB;
    #pragma unroll
    for (int i = 0; i < 16; ++i) {
        int e = base + i * 256 + t;
        if (e < E) atomicAdd(&h[dst[e] >> BKSH], 1);
    }
    __syncthreads();
    for (int i = t; i < NBK; i += 256) ghist[(size_t)i * BLK + b] = h[i];
}

// ---- exclusive scan phases (partial; block-sum add folded into readers) ----
__global__ void gscan1(const int* __restrict__ in, int* __restrict__ out,
                       int* __restrict__ bsums, int M) {
    __shared__ int tmp[256];
    int i = blockIdx.x * 256 + threadIdx.x;
    int v = (i < M) ? in[i] : 0;
    tmp[threadIdx.x] = v; __syncthreads();
    for (int off = 1; off < 256; off <<= 1) {
        int t = (threadIdx.x >= off) ? tmp[threadIdx.x - off] : 0;
        __syncthreads();
        tmp[threadIdx.x] += t;
        __syncthreads();
    }
    if (i < M) out[i] = tmp[threadIdx.x] - v;
    if (threadIdx.x == 255) bsums[blockIdx.x] = tmp[255];
}

__global__ void gscan2(int* __restrict__ bsums, int nb) {   // 1 block, 1024 thr
    __shared__ int tmp[1024];
    int v = (threadIdx.x < nb) ? bsums[threadIdx.x] : 0;
    tmp[threadIdx.x] = v; __syncthreads();
    for (int off = 1; off < 1024; off <<= 1) {
        int t = (threadIdx.x >= off) ? tmp[threadIdx.x - off] : 0;
        __syncthreads();
        tmp[threadIdx.x] += t;
        __syncthreads();
    }
    if (threadIdx.x < nb) bsums[threadIdx.x] = tmp[threadIdx.x] - v;
}

// ---- scatter edges into bucket-sorted tmp (offsets = goff + gbsums) ----
__global__ void bscatter(const int* __restrict__ src, const int* __restrict__ dst,
                         const int* __restrict__ goff, const int* __restrict__ gbsums,
                         uint2* __restrict__ tmp, int E, int NBK, int BLK) {
    __shared__ int off[512];
    int t = threadIdx.x, b = blockIdx.x;
    for (int i = t; i < NBK; i += 256) {
        size_t m = (size_t)i * BLK + b;
        off[i] = goff[m] + gbsums[m >> 8];
    }
    __syncthreads();
    int base = b * EPB;
    #pragma unroll
    for (int i = 0; i < 16; ++i) {
        int e = base + i * 256 + t;
        if (e < E) {
            int d = dst[e];
            int p = atomicAdd(&off[d >> BKSH], 1);   // LDS-local
            tmp[p] = make_uint2((unsigned)src[e], (unsigned)d);
        }
    }
}

// ---- per-bucket: count + LDS scan -> rowptr + dinv (replaces 4 kernels) ----
__global__ void bucketA(const uint2* __restrict__ tmp, const int* __restrict__ goff,
                        const int* __restrict__ gbsums, int* __restrict__ rowptr,
                        float* __restrict__ dinv, int N, int NBK, int BLK, int E) {
    __shared__ int lc[256], sc[256];
    int b = blockIdx.x, t = threadIdx.x;
    lc[t] = 0; __syncthreads();
    size_t m0 = (size_t)b * BLK;
    int p0 = goff[m0] + gbsums[m0 >> 8];
    int p1 = E;
    if (b + 1 < NBK) { size_t m1 = (size_t)(b + 1) * BLK; p1 = goff[m1] + gbsums[m1 >> 8]; }
    for (int p = p0 + t; p < p1; p += 256) atomicAdd(&lc[tmp[p].y & 255], 1);
    __syncthreads();
    int v = lc[t];
    sc[t] = v; __syncthreads();
    for (int off = 1; off < 256; off <<= 1) {
        int tv = (t >= off) ? sc[t - off] : 0;
        __syncthreads();
        sc[t] += tv;
        __syncthreads();
    }
    int node = (b << BKSH) + t;
    if (node < N) {
        rowptr[node] = p0 + (sc[t] - v);
        dinv[node]   = rsqrtf((float)(v + 1));
    }
    if (b == 0 && t == 0) rowptr[N] = E;
}

// ---- place edges (dense window) + fused layer-1 aggregation ----
__global__ void fillB(const uint2* __restrict__ tmp, const int* __restrict__ goff,
                      const int* __restrict__ gbsums, const int* __restrict__ rowptr,
                      const float* __restrict__ dinv, const float* __restrict__ x,
                      float2* __restrict__ ew, float4* __restrict__ a1,
                      int N, int NBK, int BLK, int E) {
    __shared__ int   lfill[256];
    __shared__ int   rbase[257];
    __shared__ float ldv[256];
    int b = blockIdx.x, t = threadIdx.x;
    int node0 = b << BKSH;
    lfill[t] = 0;
    int node = node0 + t;
    rbase[t] = rowptr[min(node, N)];
    ldv[t]   = dinv[min(node, N - 1)];
    if (t == 0) rbase[256] = rowptr[min(node0 + 256, N)];
    __syncthreads();
    size_t m0 = (size_t)b * BLK;
    int p0 = goff[m0] + gbsums[m0 >> 8];
    int p1 = E;
    if (b + 1 < NBK) { size_t m1 = (size_t)(b + 1) * BLK; p1 = goff[m1] + gbsums[m1 >> 8]; }
    for (int p = p0 + t; p < p1; p += 256) {
        uint2 e = tmp[p];
        int s = (int)e.x, dl = (int)(e.y & 255);
        float w = dinv[s] * ldv[dl];
        int pos = rbase[dl] + atomicAdd(&lfill[dl], 1);
        ew[pos] = make_float2(__int_as_float(s), w);
    }
    __syncthreads();
    // fused agg3: 16 lane-groups sweep the bucket's 256 nodes (ew L2-hot)
    int grp = t >> 4, sub = t & 15;
    for (int ni = grp; ni < 256; ni += 16) {
        int n = node0 + ni;
        if (n >= N) break;
        int q0 = rbase[ni], q1 = rbase[ni + 1];
        float ax = 0.f, ay = 0.f, az = 0.f;
        for (int p = q0 + sub; p < q1; p += 16) {
            float2 e = ew[p];
            int s = __float_as_int(e.x);
            ax = fmaf(e.y, x[s*3+0], ax);
            ay = fmaf(e.y, x[s*3+1], ay);
            az = fmaf(e.y, x[s*3+2], az);
        }
        #pragma unroll
        for (int off = 8; off; off >>= 1) {
            ax += __shfl_down(ax, off, 16);
            ay += __shfl_down(ay, off, 16);
            az += __shfl_down(az, off, 16);
        }
        if (sub == 0) {
            float dv = ldv[ni], sw = dv * dv;
            a1[n] = make_float4(fmaf(sw, x[n*3+0], ax),
                                fmaf(sw, x[n*3+1], ay),
                                fmaf(sw, x[n*3+2], az), sw);
        }
    }
}

// wc[k] = W3[k][:] @ Wh; wc[64] = b3 @ Wh + bh
__global__ void fold_head(const float* __restrict__ W3, const float* __restrict__ b3,
                          const float* __restrict__ Wh, const float* __restrict__ bh,
                          float* __restrict__ wc) {
    int k = threadIdx.x;              // 64
    float acc = 0.0f;
    for (int f = 0; f < 64; f++) acc += W3[k*64+f] * Wh[f];
    wc[k] = acc;
    if (k == 0) {
        float bb = bh[0];
        for (int f = 0; f < 64; f++) bb += b3[f] * Wh[f];
        wc[64] = bb;
    }
}

// z[n] = relu( (S relu(a1@W1+b1))[n] @ W2 + b2 ) @ wc   (cross-node prefetch)
__global__ void fused_l2l3(const float2* __restrict__ ew, const int* __restrict__ rowptr,
                           const float4* __restrict__ a1, const float* __restrict__ W1,
                           const float* __restrict__ b1, const float* __restrict__ W2,
                           const float* __restrict__ b2, const float* __restrict__ wc,
                           float* __restrict__ z, int N, int E) {
    __shared__ float Wl[64*64];
    __shared__ float a2buf[4][64];
    const int tid = threadIdx.x;
    for (int i = tid; i < 4096; i += 256) Wl[i] = W2[i];
    const int lane = tid & 63;
    const int wv   = tid >> 6;
    const float w10 = W1[lane], w11 = W1[64+lane], w12 = W1[128+lane];
    const float b1f = b1[lane], b2f = b2[lane], wcf = wc[lane];
    const int NPW = 8;
    const int n0 = (blockIdx.x * 4 + wv) * NPW;
    int   rpl = rowptr[min(n0 + lane, N)];         // lanes 0..9 used
    float4 sg = a1[min(n0 + lane, N - 1)];         // lanes 0..7 used (self terms)
    __syncthreads();
    // prologue: load chunk0 of node n0
    float2 e_cur; float4 g_cur;
    {
        int p0 = rfl(__shfl(rpl, 0));
        e_cur = ew[min(p0 + lane, E - 1)];
        g_cur = a1[__float_as_int(e_cur.x)];
    }
    for (int cur = 0; cur < NPW; ++cur) {
        int n = n0 + cur;
        if (n >= N) break;
        int p0 = rfl(__shfl(rpl, cur));
        int p1 = rfl(__shfl(rpl, cur + 1));
        // issue next node's ew load early (covered by first-half edges)
        float2 e_nxt = e_cur; float4 g_nxt = g_cur;
        bool hasnext = (cur + 1 < NPW) && (n + 1 < N);   // wave-uniform
        if (hasnext) {
            int q0 = rfl(__shfl(rpl, cur + 1));
            e_nxt = ew[min(q0 + lane, E - 1)];
        }
        // self-loop term
        float sx = rlane(sg.x, cur), sy = rlane(sg.y, cur);
        float sz2 = rlane(sg.z, cur), sw = rlane(sg.w, cur);
        float ts = fmaf(sz2, w12, fmaf(sy, w11, fmaf(sx, w10, b1f)));
        float acc = sw * fmaxf(ts, 0.f);
        int m = p1 - p0; if (m > 64) m = 64;   // uniform trip (SGPR)
        int j = 0;
        int mf = m < 8 ? m : 8;
        for (; j < mf; ++j) {                  // first half: covers e_nxt latency
            float ex = rlane(g_cur.x, j), ey = rlane(g_cur.y, j);
            float ez = rlane(g_cur.z, j), ww = rlane(e_cur.y, j);
            float tt = fmaf(ez, w12, fmaf(ey, w11, fmaf(ex, w10, b1f)));
            acc = fmaf(ww, fmaxf(tt, 0.f), acc);
        }
        __builtin_amdgcn_sched_barrier(0);
        if (hasnext) g_nxt = a1[__float_as_int(e_nxt.x)];   // latency covered by rest+epilogue
        __builtin_amdgcn_sched_barrier(0);
        for (; j + 3 < m; j += 4) {
            #pragma unroll
            for (int u = 0; u < 4; ++u) {
                float ex = rlane(g_cur.x, j+u), ey = rlane(g_cur.y, j+u);
                float ez = rlane(g_cur.z, j+u), ww = rlane(e_cur.y, j+u);
                float tt = fmaf(ez, w12, fmaf(ey, w11, fmaf(ex, w10, b1f)));
                acc = fmaf(ww, fmaxf(tt, 0.f), acc);
            }
        }
        for (; j < m; ++j) {
            float ex = rlane(g_cur.x, j), ey = rlane(g_cur.y, j);
            float ez = rlane(g_cur.z, j), ww = rlane(e_cur.y, j);
            float tt = fmaf(ez, w12, fmaf(ey, w11, fmaf(ex, w10, b1f)));
            acc = fmaf(ww, fmaxf(tt, 0.f), acc);
        }
        // rare extra chunks (deg > 64)
        for (int pc = p0 + 64; pc < p1; pc += 64) {
            float2 e2 = ew[min(pc + lane, p1 - 1)];
            float4 g2 = a1[__float_as_int(e2.x)];
            int m2 = p1 - pc; if (m2 > 64) m2 = 64;
            for (int j2 = 0; j2 < m2; ++j2) {
                float ex = rlane(g2.x, j2), ey = rlane(g2.y, j2);
                float ez = rlane(g2.z, j2), ww = rlane(e2.y, j2);
                float tt = fmaf(ez, w12, fmaf(ey, w11, fmaf(ex, w10, b1f)));
                acc = fmaf(ww, fmaxf(tt, 0.f), acc);
            }
        }
        // a2 exchange (wave-private LDS row), then W2 matmul from LDS
        a2buf[wv][lane] = acc;
        float h = b2f;
        const float4* a4 = (const float4*)a2buf[wv];
        #pragma unroll
        for (int k4 = 0; k4 < 16; ++k4) {
            float4 a = a4[k4];
            h = fmaf(a.x, Wl[(4*k4+0)*64 + lane], h);
            h = fmaf(a.y, Wl[(4*k4+1)*64 + lane], h);
            h = fmaf(a.z, Wl[(4*k4+2)*64 + lane], h);
            h = fmaf(a.w, Wl[(4*k4+3)*64 + lane], h);
        }
        float vv = fmaxf(h, 0.f) * wcf;
        #pragma unroll
        for (int off = 32; off; off >>= 1) vv += __shfl_down(vv, off);
        if (lane == 0) z[n] = vv;
        e_cur = e_nxt; g_cur = g_nxt;
    }
}

// logits[n] = dinv^2 z[n] + sum_e w z[s] + c; 16-lane group per node
__global__ void final_wave(const float* __restrict__ z, const float2* __restrict__ ew,
                           const int* __restrict__ rowptr, const float* __restrict__ dinv,
                           const float* __restrict__ wc, float* __restrict__ out, int N) {
    int g   = (blockIdx.x * blockDim.x + threadIdx.x) >> 4;
    int sub = threadIdx.x & 15;
    if (g >= N) return;
    int p0 = rowptr[g], p1 = rowptr[g+1];
    float acc = 0.f;
    for (int p = p0 + sub; p < p1; p += 16) {
        float2 e = ew[p];
        acc = fmaf(e.y, z[__float_as_int(e.x)], acc);
    }
    #pragma unroll
    for (int off = 8; off; off >>= 1) acc += __shfl_down(acc, off, 16);
    if (sub == 0) {
        float dv = dinv[g];
        out[g] = fmaf(dv * dv, z[g], acc) + wc[64];
    }
}

extern "C" void kernel_launch(void* const* d_in, const int* in_sizes, int n_in,
                              void* d_out, int out_size, void* d_ws, size_t ws_size,
                              hipStream_t stream) {
    const float* x   = (const float*)d_in[0];
    const int*   ei  = (const int*)d_in[1];
    const float* W1  = (const float*)d_in[2];
    const float* b1  = (const float*)d_in[3];
    const float* W2  = (const float*)d_in[4];
    const float* b2  = (const float*)d_in[5];
    const float* W3  = (const float*)d_in[6];
    const float* b3  = (const float*)d_in[7];
    const float* Wh  = (const float*)d_in[8];
    const float* bh  = (const float*)d_in[9];
    float* logits = (float*)d_out;

    const int N = in_sizes[0] / 3;
    const int E = in_sizes[1] / 2;
    const int* src = ei;
    const int* dst = ei + E;

    const int NBK = (N + 255) >> BKSH;            // 391 buckets
    const int BLK = (E + EPB - 1) / EPB;          // 391 scatter blocks
    const int M   = NBK * BLK;

    float* base = (float*)d_ws;
    size_t o = 0;
    float*  dinv   = base + o; o += (size_t)N;
    o = (o + 3) & ~(size_t)3;
    float4* a1     = (float4*)(base + o); o += (size_t)4*N;
    int*    rowptr = (int*)(base + o); o += (size_t)N + 1;
    int*    gbsums = (int*)(base + o); o += 1024;
    o = (o + 1) & ~(size_t)1;
    float2* ew     = (float2*)(base + o); o += (size_t)2*E;
    uint2*  tmpb   = (uint2*)(base + o); o += (size_t)2*E;
    float*  zbuf   = base + o; o += (size_t)N;
    float*  wc     = base + o; o += 65;
    int*    ghist  = (int*)(base + o); o += (size_t)M;
    int*    goff   = (int*)(base + o); o += (size_t)M;

    const int BS = 256;
    int gM   = (M + BS - 1) / BS;
    int g16  = ((size_t)N * 16 + BS - 1) / BS;
    int gFU  = (N + 31) / 32;

    bhist    <<<BLK, BS, 0, stream>>>(dst, ghist, E, NBK, BLK);
    gscan1   <<<gM,  BS, 0, stream>>>(ghist, goff, gbsums, M);
    gscan2   <<<1, 1024, 0, stream>>>(gbsums, gM);
    bscatter <<<BLK, BS, 0, stream>>>(src, dst, goff, gbsums, tmpb, E, NBK, BLK);
    bucketA  <<<NBK, BS, 0, stream>>>(tmpb, goff, gbsums, rowptr, dinv, N, NBK, BLK, E);
    fillB    <<<NBK, BS, 0, stream>>>(tmpb, goff, gbsums, rowptr, dinv, x, ew, a1, N, NBK, BLK, E);

    fold_head  <<<1, 64, 0, stream>>>(W3, b3, Wh, bh, wc);
    fused_l2l3 <<<gFU, BS, 0, stream>>>(ew, rowptr, a1, W1, b1, W2, b2, wc, zbuf, N, E);
    final_wave <<<g16, BS, 0, stream>>>(zbuf, ew, rowptr, dinv, wc, logits, N);
}